// Round 3
// baseline (2344.341 us; speedup 1.0000x reference)
//
#include <hip/hip_runtime.h>

#define DI __device__ __forceinline__

typedef float f32x4 __attribute__((ext_vector_type(4)));
typedef __bf16 bf16x8 __attribute__((ext_vector_type(8)));
typedef __bf16 bf16x4 __attribute__((ext_vector_type(4)));

static DI f32x4 mfma_bf16(bf16x8 a, bf16x8 b, f32x4 c) {
    return __builtin_amdgcn_mfma_f32_16x16x32_bf16(a, b, c, 0, 0, 0);
}
static DI bf16x8 ldb8(const __bf16* p) { return *(const bf16x8*)p; }
static DI float sigf(float x) { return 1.0f / (1.0f + expf(-x)); }

// ---- device-coherent (cross-XCD) access helpers: relaxed agent-scope atomics.
// These lower to global_load/store with sc0 sc1 flags (coherent at fabric),
// WITHOUT any buffer_inv / buffer_wbl2 cache maintenance.
static DI unsigned ldc_u32(const void* p) {
    return __hip_atomic_load((const unsigned*)p, __ATOMIC_RELAXED, __HIP_MEMORY_SCOPE_AGENT);
}
static DI void stc_u32(void* p, unsigned v) {
    __hip_atomic_store((unsigned*)p, v, __ATOMIC_RELAXED, __HIP_MEMORY_SCOPE_AGENT);
}
static DI void stc_u16(void* p, unsigned short v) {
    __hip_atomic_store((unsigned short*)p, v, __ATOMIC_RELAXED, __HIP_MEMORY_SCOPE_AGENT);
}
static DI bf16x8 ldc_b8(const __bf16* p) {
    union { unsigned u[4]; bf16x8 v; } r;
    const unsigned* q = (const unsigned*)p;
    r.u[0] = ldc_u32(q + 0);
    r.u[1] = ldc_u32(q + 1);
    r.u[2] = ldc_u32(q + 2);
    r.u[3] = ldc_u32(q + 3);
    return r.v;
}
static DI void stc_bf16(__bf16* p, float v) {
    union { __bf16 b; unsigned short s; } c; c.b = (__bf16)v;
    stc_u16(p, c.s);
}

// B=64, T=32, R=49, LOCAL=1024, QVEC=512, EMB=256, HID=512, VOCAB=10000
#define GRID_BLKS 64

// ---------------- fence-free grid barrier ----------------
// Correctness: __syncthreads() emits s_waitcnt vmcnt(0) before s_barrier, so all
// of this block's sc1 (write-through-to-fabric) stores are complete before the
// arrival atomic. Readers poll gen (relaxed, no inv) then issue sc1 loads that
// read the coherence point directly. cnt is never reset (monotonic arrivals).
static DI void gbar(unsigned* cnt, unsigned* gen, unsigned tgt) {
    __syncthreads();
    if (threadIdx.x == 0) {
        unsigned arrived = __hip_atomic_fetch_add(
            cnt, 1u, __ATOMIC_RELAXED, __HIP_MEMORY_SCOPE_AGENT) + 1;
        if (arrived == (unsigned)GRID_BLKS * tgt) {
            __hip_atomic_store(gen, tgt, __ATOMIC_RELAXED, __HIP_MEMORY_SCOPE_AGENT);
        } else {
            while (__hip_atomic_load(gen, __ATOMIC_RELAXED, __HIP_MEMORY_SCOPE_AGENT) < tgt)
                __builtin_amdgcn_s_sleep(1);
        }
    }
    __syncthreads();
}

// ---------------- conversions + gathers (z-dispatched) ----------------
__global__ void convert_kernel(
    const float* Wv, const float* Wih, const float* Whh,
    const float* bih, const float* bhh, const float* Wu,
    const float* emb, const int* answers, const float* localf,
    __bf16* WVo, __bf16* WGo, float* biasg, __bf16* WUo, __bf16* Yo, __bf16* LFo)
{
    int z = blockIdx.z;
    int stride = gridDim.x * blockDim.x;
    int tid0 = blockIdx.x * blockDim.x + threadIdx.x;
    if (z == 0) {
        const int N = 10112 * 512;
        for (int i = tid0; i < N; i += stride) {
            int v = i >> 9, h = i & 511;
            WVo[i] = (v < 10000) ? (__bf16)Wv[v * 512 + h] : (__bf16)0.0f;
        }
    } else if (z == 1) {
        // Gate-permuted concat [W_ih | W_hh] -> WG [2048 perm rows, 1280]
        // perm row n <-> original row r = (n&3)*512 + (n>>2)
        const int N = 2048 * 1280;
        for (int i = tid0; i < N; i += stride) {
            int n = i / 1280, k = i - n * 1280;
            int r = (n & 3) * 512 + (n >> 2);
            float val = (k < 768) ? Wih[r * 768 + k] : Whh[r * 512 + (k - 768)];
            WGo[i] = (__bf16)val;
        }
        for (int n = tid0; n < 2048; n += stride) {
            int r = (n & 3) * 512 + (n >> 2);
            biasg[n] = bih[r] + bhh[r];
        }
    } else if (z == 2) {
        const int N = 512 * 1536;
        for (int i = tid0; i < N; i += stride) WUo[i] = (__bf16)Wu[i];
    } else if (z == 3) {
        // y_seq gather: t=0 -> emb[1]; t>=1 -> emb[answers[b, t-1]]   [32,64,256]
        const int N = 32 * 64 * 256;
        for (int i = tid0; i < N; i += stride) {
            int t = i >> 14;
            int b = (i >> 8) & 63;
            int e = i & 255;
            int tok = (t == 0) ? 1 : answers[b * 32 + (t - 1)];
            Yo[i] = (__bf16)emb[tok * 256 + e];
        }
    } else {
        const int N = 64 * 49 * 1024;
        for (int i = tid0; i < N; i += stride) LFo[i] = (__bf16)localf[i];
    }
}

// ---------------- init: h0 = q@Wh^T, c0 = q@Wc^T, o0 = g@Wg2o^T + b ----------------
__global__ void init_kernel(
    const float* q, const float* g,
    const float* Wh, const float* Wc, const float* Wg2o, const float* bg2o,
    __bf16* h0b, float* c0f, __bf16* o0b)
{
    int z = blockIdx.z;
    const float* A; const float* B; int K;
    if (z == 0)      { A = q; B = Wh;   K = 512; }
    else if (z == 1) { A = q; B = Wc;   K = 512; }
    else             { A = g; B = Wg2o; K = 2048; }
    int n0 = blockIdx.x * 64, m0 = blockIdx.y * 16;
    __shared__ float As[32][16];
    __shared__ float Bs[32][64];
    int tid = threadIdx.x;
    int n = tid & 63, tyq = tid >> 6;
    float acc[4] = {0.f, 0.f, 0.f, 0.f};
    for (int k0 = 0; k0 < K; k0 += 32) {
        {
            int idx = tid * 2, row = idx >> 5, kk = idx & 31;
            const float* ar = A + (m0 + row) * K + k0 + kk;
            As[kk][row] = ar[0];
            As[kk + 1][row] = ar[1];
        }
        {
            int row = tid >> 2, kk = (tid & 3) * 8;
            const float* br = B + (n0 + row) * K + k0 + kk;
            float4 v0 = *(const float4*)br;
            float4 v1 = *(const float4*)(br + 4);
            Bs[kk + 0][row] = v0.x; Bs[kk + 1][row] = v0.y;
            Bs[kk + 2][row] = v0.z; Bs[kk + 3][row] = v0.w;
            Bs[kk + 4][row] = v1.x; Bs[kk + 5][row] = v1.y;
            Bs[kk + 6][row] = v1.z; Bs[kk + 7][row] = v1.w;
        }
        __syncthreads();
        #pragma unroll
        for (int k = 0; k < 32; k++) {
            float4 a = *(const float4*)&As[k][tyq * 4];
            float b = Bs[k][n];
            acc[0] += a.x * b; acc[1] += a.y * b; acc[2] += a.z * b; acc[3] += a.w * b;
        }
        __syncthreads();
    }
    int ng = n0 + n;
    #pragma unroll
    for (int i = 0; i < 4; i++) {
        int m = m0 + tyq * 4 + i;
        float v = acc[i];
        if (z == 0)      { h0b[m * 512 + ng] = (__bf16)v; }
        else if (z == 1) { c0f[m * 512 + ng] = v; }
        else             { o0b[m * 512 + ng] = (__bf16)(v + bg2o[ng]); }
    }
}

// ---------------- attn_proj = localf @ W_attn^T -> bf16 [3136,512], MFMA ----------------
__global__ __launch_bounds__(256) void attnproj_kernel(
    const float* Af, const float* Bf, __bf16* APo)
{
    __shared__ __bf16 As[64][72];
    __shared__ __bf16 Bs[64][72];
    int tid = threadIdx.x;
    int m0 = blockIdx.x * 64, n0 = blockIdx.y * 64;
    int w = tid >> 6, lane = tid & 63, row16 = lane & 15, kg = lane >> 4;
    f32x4 acc[4] = {};
    for (int k0 = 0; k0 < 1024; k0 += 64) {
        int r = tid >> 2, col = (tid & 3) * 16;
        const float* ap = Af + (size_t)(m0 + r) * 1024 + k0 + col;
        const float* bp = Bf + (size_t)(n0 + r) * 1024 + k0 + col;
        bf16x8 va0, va1, vb0, vb1;
        #pragma unroll
        for (int u = 0; u < 8; u++) {
            va0[u] = (__bf16)ap[u]; va1[u] = (__bf16)ap[u + 8];
            vb0[u] = (__bf16)bp[u]; vb1[u] = (__bf16)bp[u + 8];
        }
        *(bf16x8*)&As[r][col] = va0; *(bf16x8*)&As[r][col + 8] = va1;
        *(bf16x8*)&Bs[r][col] = vb0; *(bf16x8*)&Bs[r][col + 8] = vb1;
        __syncthreads();
        #pragma unroll
        for (int kt = 0; kt < 2; kt++) {
            bf16x8 af = *(const bf16x8*)&As[w * 16 + row16][kt * 32 + kg * 8];
            #pragma unroll
            for (int j = 0; j < 4; j++) {
                bf16x8 bfv = *(const bf16x8*)&Bs[j * 16 + row16][kt * 32 + kg * 8];
                acc[j] = mfma_bf16(af, bfv, acc[j]);
            }
        }
        __syncthreads();
    }
    #pragma unroll
    for (int j = 0; j < 4; j++)
        #pragma unroll
        for (int r = 0; r < 4; r++)
            APo[(size_t)(m0 + w * 16 + kg * 4 + r) * 512 + n0 + j * 16 + row16] =
                (__bf16)acc[j][r];
}

// ---------------- persistent step-loop kernel (grid = 64 blocks) ----------------
// Cross-block mutable state (HB, OB, AB) uses sc1 coherent access; read-only
// weights/activations use normal cached loads (stay L2-resident, no invalidates).
// CF (cell state) is block-local: plain cached access.
__global__ __launch_bounds__(256) void loop_kernel(
    const __bf16* Yall, const __bf16* WG, const float* BG,
    const __bf16* WU, const float* bu,
    const __bf16* APb, const __bf16* LFb, const float* localf, int use_lfb,
    __bf16* OB, __bf16* HB, float* CF, __bf16* AB,
    unsigned* bar_cnt, unsigned* bar_gen)
{
    __shared__ float SH[4][64][33];
    __shared__ float esh[64];
    __shared__ float ash[64];
    int tid = threadIdx.x;
    int blk = blockIdx.x;
    int w = tid >> 6, lane = tid & 63, row16 = lane & 15, kg = lane >> 4;
    unsigned bgen = 0;

    for (int t = 0; t < 32; t++) {
        int hprev = t & 1, hcur = (t + 1) & 1;
        // ---- Phase A: gates = [y|o|h] @ WG^T (K-split over waves), LSTM -> h,c ----
        {
            const __bf16* Yt  = Yall + t * 16384;
            const __bf16* OBp = OB + t * 32768;
            const __bf16* HBp = HB + hprev * 32768;
            const float*  CFp = CF + hprev * 32768;
            float*  CFc = CF + hcur * 32768;
            __bf16* HBc = HB + hcur * 32768;
            int n0 = blk * 32;
            f32x4 acc[4][2] = {};
            for (int kt = w * 10; kt < w * 10 + 10; kt++) {
                int k0 = kt * 32;
                bf16x8 af[4], bfv[2];
                if (k0 < 256) {
                    #pragma unroll
                    for (int mt = 0; mt < 4; mt++)
                        af[mt] = ldb8(Yt + (mt * 16 + row16) * 256 + k0 + kg * 8);
                } else if (k0 < 768) {
                    #pragma unroll
                    for (int mt = 0; mt < 4; mt++)
                        af[mt] = ldc_b8(OBp + (mt * 16 + row16) * 512 + (k0 - 256) + kg * 8);
                } else {
                    #pragma unroll
                    for (int mt = 0; mt < 4; mt++)
                        af[mt] = ldc_b8(HBp + (mt * 16 + row16) * 512 + (k0 - 768) + kg * 8);
                }
                #pragma unroll
                for (int nt = 0; nt < 2; nt++)
                    bfv[nt] = ldb8(WG + (size_t)(n0 + nt * 16 + row16) * 1280 + k0 + kg * 8);
                #pragma unroll
                for (int mt = 0; mt < 4; mt++)
                    #pragma unroll
                    for (int nt = 0; nt < 2; nt++)
                        acc[mt][nt] = mfma_bf16(af[mt], bfv[nt], acc[mt][nt]);
            }
            #pragma unroll
            for (int mt = 0; mt < 4; mt++)
                #pragma unroll
                for (int nt = 0; nt < 2; nt++)
                    #pragma unroll
                    for (int r = 0; r < 4; r++)
                        SH[w][mt * 16 + kg * 4 + r][nt * 16 + row16] = acc[mt][nt][r];
            __syncthreads();
            #pragma unroll
            for (int q = 0; q < 2; q++) {
                int idx = q * 256 + tid;
                int bb = idx >> 3, ul = idx & 7;
                float gv[4];
                #pragma unroll
                for (int g = 0; g < 4; g++) {
                    int col = ul * 4 + g;
                    gv[g] = SH[0][bb][col] + SH[1][bb][col] + SH[2][bb][col] + SH[3][bb][col]
                          + BG[n0 + col];
                }
                int j = blk * 8 + ul;
                float cp = CFp[bb * 512 + j];
                float cn = sigf(gv[1]) * cp + sigf(gv[0]) * tanhf(gv[2]);
                float hn = sigf(gv[3]) * tanhf(cn);
                CFc[bb * 512 + j] = cn;              // block-local: plain store
                stc_bf16(&HBc[bb * 512 + j], hn);    // cross-block: coherent store
            }
        }
        gbar(bar_cnt, bar_gen, ++bgen);

        // ---- Phase B: attention (block = batch) -> a (bf16) ----
        {
            int b = blk;
            const __bf16* hb = HB + hcur * 32768 + b * 512;
            for (int r = w; r < 49; r += 4) {
                bf16x8 ap8 = ldb8(APb + (size_t)(b * 49 + r) * 512 + lane * 8);
                bf16x8 h8  = ldc_b8(hb + lane * 8);
                float s = 0.f;
                #pragma unroll
                for (int u = 0; u < 8; u++) s += (float)ap8[u] * (float)h8[u];
                #pragma unroll
                for (int off = 32; off > 0; off >>= 1) s += __shfl_xor(s, off);
                if (lane == 0) esh[r] = s;
            }
            __syncthreads();
            if (tid < 64) {
                float v = (tid < 49) ? esh[tid] : -3.0e38f;
                float mx = v;
                #pragma unroll
                for (int off = 32; off > 0; off >>= 1) mx = fmaxf(mx, __shfl_xor(mx, off));
                float ex = (tid < 49) ? expf(v - mx) : 0.0f;
                float sm = ex;
                #pragma unroll
                for (int off = 32; off > 0; off >>= 1) sm += __shfl_xor(sm, off);
                if (tid < 49) ash[tid] = ex / sm;
            }
            __syncthreads();
            float a0 = 0.f, a1 = 0.f, a2 = 0.f, a3 = 0.f;
            if (use_lfb) {
                const __bf16* lb = LFb + (size_t)b * 49 * 1024 + tid * 4;
                for (int r = 0; r < 49; r++) {
                    float wt = ash[r];
                    bf16x4 lf = *(const bf16x4*)(lb + r * 1024);
                    a0 += wt * (float)lf[0]; a1 += wt * (float)lf[1];
                    a2 += wt * (float)lf[2]; a3 += wt * (float)lf[3];
                }
            } else {
                const float* lb = localf + (size_t)b * 49 * 1024 + tid * 4;
                for (int r = 0; r < 49; r++) {
                    float wt = ash[r];
                    float4 lf = *(const float4*)(lb + r * 1024);
                    a0 += wt * lf.x; a1 += wt * lf.y; a2 += wt * lf.z; a3 += wt * lf.w;
                }
            }
            union { __bf16 b4[4]; unsigned u2[2]; } pk;
            pk.b4[0] = (__bf16)a0; pk.b4[1] = (__bf16)a1;
            pk.b4[2] = (__bf16)a2; pk.b4[3] = (__bf16)a3;
            unsigned* ao = (unsigned*)(AB + b * 1024 + tid * 4);
            stc_u32(ao + 0, pk.u2[0]);
            stc_u32(ao + 1, pk.u2[1]);
        }
        gbar(bar_cnt, bar_gen, ++bgen);

        // ---- Phase C: o = tanh([a|h] @ Wu^T + b_u) ----
        if (blk < 32) {
            int tile = blk * 4 + w;         // 0..127
            int mt = tile & 3;
            int n0c = (tile >> 2) * 16;
            const __bf16* HBc = HB + hcur * 32768;
            f32x4 acc = {};
            for (int kt = 0; kt < 48; kt++) {
                int k0 = kt * 32;
                bf16x8 af;
                if (k0 < 1024) af = ldc_b8(AB + (mt * 16 + row16) * 1024 + k0 + kg * 8);
                else           af = ldc_b8(HBc + (mt * 16 + row16) * 512 + (k0 - 1024) + kg * 8);
                bf16x8 bfv = ldb8(WU + (size_t)(n0c + row16) * 1536 + k0 + kg * 8);
                acc = mfma_bf16(af, bfv, acc);
            }
            int n = n0c + row16;
            float bun = bu[n];
            __bf16* Oo = OB + (t + 1) * 32768;
            #pragma unroll
            for (int r = 0; r < 4; r++) {
                int m = mt * 16 + kg * 4 + r;
                stc_bf16(&Oo[m * 512 + n], tanhf(acc[r] + bun));
            }
        }
        gbar(bar_cnt, bar_gen, ++bgen);
    }
}

// ---------------- vocab: logits = O @ Wv^T + b, 128x128 LDS-tiled MFMA ----------------
__global__ __launch_bounds__(256) void vocab_kernel(
    const __bf16* A, const __bf16* Wv, const float* bv, float* out)
{
    __shared__ __bf16 As[128][72];
    __shared__ __bf16 Bs[128][72];
    int tid = threadIdx.x;
    int m0 = blockIdx.x * 128;   // 16 mblk (fast) for B-tile L2 reuse
    int n0 = blockIdx.y * 128;   // 79 nblk
    int w = tid >> 6, lane = tid & 63, row16 = lane & 15, kg = lane >> 4;
    int mw = (w & 1) * 64, nw = (w >> 1) * 64;
    f32x4 acc[4][4] = {};
    for (int k0 = 0; k0 < 512; k0 += 64) {
        #pragma unroll
        for (int q = 0; q < 2; q++) {
            int c = q * 256 + tid;
            int r = c >> 2, col = (c & 3) * 16;
            bf16x8 v0 = ldb8(A + (size_t)(m0 + r) * 512 + k0 + col);
            bf16x8 v1 = ldb8(A + (size_t)(m0 + r) * 512 + k0 + col + 8);
            *(bf16x8*)&As[r][col] = v0;
            *(bf16x8*)&As[r][col + 8] = v1;
            bf16x8 u0 = ldb8(Wv + (size_t)(n0 + r) * 512 + k0 + col);
            bf16x8 u1 = ldb8(Wv + (size_t)(n0 + r) * 512 + k0 + col + 8);
            *(bf16x8*)&Bs[r][col] = u0;
            *(bf16x8*)&Bs[r][col + 8] = u1;
        }
        __syncthreads();
        #pragma unroll
        for (int kt = 0; kt < 2; kt++) {
            bf16x8 af[4], bfr[4];
            #pragma unroll
            for (int i = 0; i < 4; i++)
                af[i] = *(const bf16x8*)&As[mw + i * 16 + row16][kt * 32 + kg * 8];
            #pragma unroll
            for (int j = 0; j < 4; j++)
                bfr[j] = *(const bf16x8*)&Bs[nw + j * 16 + row16][kt * 32 + kg * 8];
            #pragma unroll
            for (int i = 0; i < 4; i++)
                #pragma unroll
                for (int j = 0; j < 4; j++)
                    acc[i][j] = mfma_bf16(af[i], bfr[j], acc[i][j]);
        }
        __syncthreads();
    }
    #pragma unroll
    for (int j = 0; j < 4; j++) {
        int n = n0 + nw + j * 16 + row16;
        if (n < 10000) {
            float bvn = bv[n];
            #pragma unroll
            for (int i = 0; i < 4; i++) {
                #pragma unroll
                for (int r = 0; r < 4; r++) {
                    int m = m0 + mw + i * 16 + kg * 4 + r;   // m = t*64 + b
                    int tt = m >> 6, b = m & 63;
                    out[(size_t)(b * 32 + tt) * 10000 + n] = acc[i][j][r] + bvn;
                }
            }
        }
    }
}

extern "C" void kernel_launch(void* const* d_in, const int* in_sizes, int n_in,
                              void* d_out, int out_size, void* d_ws, size_t ws_size,
                              hipStream_t stream) {
    (void)in_sizes; (void)n_in; (void)out_size;
    const float* localf  = (const float*)d_in[0];
    const float* globalf = (const float*)d_in[1];
    const float* qvec    = (const float*)d_in[2];
    const int*   answers = (const int*)d_in[3];
    const float* emb     = (const float*)d_in[4];
    const float* Wg2o    = (const float*)d_in[5];
    const float* bg2o    = (const float*)d_in[6];
    const float* Wh      = (const float*)d_in[7];
    const float* Wc      = (const float*)d_in[8];
    const float* Wih     = (const float*)d_in[9];
    const float* Whh     = (const float*)d_in[10];
    const float* bih     = (const float*)d_in[11];
    const float* bhh     = (const float*)d_in[12];
    const float* Wattn   = (const float*)d_in[13];
    const float* Wu      = (const float*)d_in[14];
    const float* bu      = (const float*)d_in[15];
    const float* Wvocab  = (const float*)d_in[16];
    const float* bvocab  = (const float*)d_in[17];
    float* out = (float*)d_out;

    char* ws = (char*)d_ws;
    __bf16* WV  = (__bf16*)(ws + 0);          // 10112*512 bf16 (zero-padded rows)
    __bf16* WG  = (__bf16*)(ws + 10354688);   // 2048*1280 bf16 (gate-permuted [W_ih|W_hh])
    __bf16* WU  = (__bf16*)(ws + 15597568);   // 512*1536 bf16
    __bf16* Y   = (__bf16*)(ws + 17170432);   // 32*64*256 bf16
    float*  BG  = (float*) (ws + 18219008);   // 2048 f32 (b_ih+b_hh, permuted)
    __bf16* OB  = (__bf16*)(ws + 18227200);   // 33*64*512 bf16 (o slots; slot0 = o0)
    __bf16* HB  = (__bf16*)(ws + 20389888);   // 2*64*512 bf16 (h ping-pong)
    float*  CF  = (float*) (ws + 20520960);   // 2*64*512 f32 (c ping-pong)
    __bf16* APb = (__bf16*)(ws + 20783104);   // 64*49*512 bf16 (attn_proj)
    __bf16* AB  = (__bf16*)(ws + 23994368);   // 64*1024 bf16 (attended features)
    unsigned* BAR = (unsigned*)(ws + 24125440); // 256 B barrier state
    __bf16* LFb = (__bf16*)(ws + 24125696);   // 64*49*1024 bf16 (optional)
    int use_lfb = (ws_size >= (size_t)30548224) ? 1 : 0;

    hipMemsetAsync(BAR, 0, 256, stream);
    convert_kernel<<<dim3(1024, 1, use_lfb ? 5 : 4), 256, 0, stream>>>(
        Wvocab, Wih, Whh, bih, bhh, Wu, emb, answers, localf,
        WV, WG, BG, WU, Y, LFb);
    init_kernel<<<dim3(8, 4, 3), 256, 0, stream>>>(
        qvec, globalf, Wh, Wc, Wg2o, bg2o, HB, CF, OB);
    attnproj_kernel<<<dim3(49, 8), 256, 0, stream>>>(localf, Wattn, APb);
    loop_kernel<<<GRID_BLKS, 256, 0, stream>>>(
        Y, WG, BG, WU, bu, APb, LFb, localf, use_lfb,
        OB, HB, CF, AB, BAR + 0, BAR + 1);
    vocab_kernel<<<dim3(16, 79), 256, 0, stream>>>(OB + 32768, WV, bvocab, out);
}

// Round 4
// 1557.350 us; speedup vs baseline: 1.5053x; 1.5053x over previous
//
#include <hip/hip_runtime.h>

#define DI __device__ __forceinline__

typedef float f32x4 __attribute__((ext_vector_type(4)));
typedef __bf16 bf16x8 __attribute__((ext_vector_type(8)));
typedef __bf16 bf16x4 __attribute__((ext_vector_type(4)));

static DI f32x4 mfma_bf16(bf16x8 a, bf16x8 b, f32x4 c) {
    return __builtin_amdgcn_mfma_f32_16x16x32_bf16(a, b, c, 0, 0, 0);
}
static DI bf16x8 ldb8(const __bf16* p) { return *(const bf16x8*)p; }
static DI float sigf(float x) { return 1.0f / (1.0f + expf(-x)); }

// sc1 coherent (write-through to memory-side cache) stores; relaxed agent atomics.
static DI void stc_u32(void* p, unsigned v) {
    __hip_atomic_store((unsigned*)p, v, __ATOMIC_RELAXED, __HIP_MEMORY_SCOPE_AGENT);
}
static DI void stc_u16(void* p, unsigned short v) {
    __hip_atomic_store((unsigned short*)p, v, __ATOMIC_RELAXED, __HIP_MEMORY_SCOPE_AGENT);
}
static DI void stc_bf16(__bf16* p, float v) {
    union { __bf16 b; unsigned short s; } c; c.b = (__bf16)v;
    stc_u16(p, c.s);
}

// B=64, T=32, R=49, LOCAL=1024, QVEC=512, EMB=256, HID=512, VOCAB=10000
#define GRID_BLKS 64

// ---------------- RMW-free distributed flag barrier ----------------
// Arrival: ONE sc1 store to own flag (parallel across blocks, no same-address
// RMW serialization). Detection: wave 0 polls all 64 flags, one per lane.
// __syncthreads() before the flag store drains this block's sc1 data stores
// (vmcnt(0)) so data is at the coherence point before the flag is visible.
static DI void gbar(unsigned* FL, int blk, unsigned tgt) {
    __syncthreads();
    if (threadIdx.x < 64) {
        if (threadIdx.x == 0)
            __hip_atomic_store(&FL[blk], tgt, __ATOMIC_RELAXED, __HIP_MEMORY_SCOPE_AGENT);
        for (;;) {
            unsigned f = __hip_atomic_load(&FL[threadIdx.x], __ATOMIC_RELAXED,
                                           __HIP_MEMORY_SCOPE_AGENT);
            if (__all(f >= tgt)) break;
            __builtin_amdgcn_s_sleep(1);
        }
    }
    __syncthreads();
}

// ---------------- conversions + gathers (z-dispatched) ----------------
__global__ void convert_kernel(
    const float* Wih, const float* Whh,
    const float* bih, const float* bhh, const float* Wu,
    const float* emb, const int* answers, const float* localf,
    __bf16* WGo, float* biasg, __bf16* WUo, __bf16* Yo, __bf16* LFo)
{
    int z = blockIdx.z;
    int stride = gridDim.x * blockDim.x;
    int tid0 = blockIdx.x * blockDim.x + threadIdx.x;
    if (z == 0) {
        // Gate-permuted concat [W_ih | W_hh] -> WG [2048 perm rows, 1280]
        // perm row n <-> original row r = (n&3)*512 + (n>>2)  (unit-major)
        const int N = 2048 * 1280;
        for (int i = tid0; i < N; i += stride) {
            int n = i / 1280, k = i - n * 1280;
            int r = (n & 3) * 512 + (n >> 2);
            float val = (k < 768) ? Wih[r * 768 + k] : Whh[r * 512 + (k - 768)];
            WGo[i] = (__bf16)val;
        }
        for (int n = tid0; n < 2048; n += stride) {
            int r = (n & 3) * 512 + (n >> 2);
            biasg[n] = bih[r] + bhh[r];
        }
    } else if (z == 1) {
        const int N = 512 * 1536;
        for (int i = tid0; i < N; i += stride) WUo[i] = (__bf16)Wu[i];
    } else if (z == 2) {
        // y_seq gather: t=0 -> emb[1]; t>=1 -> emb[answers[b, t-1]]   [32,64,256]
        const int N = 32 * 64 * 256;
        for (int i = tid0; i < N; i += stride) {
            int t = i >> 14;
            int b = (i >> 8) & 63;
            int e = i & 255;
            int tok = (t == 0) ? 1 : answers[b * 32 + (t - 1)];
            Yo[i] = (__bf16)emb[tok * 256 + e];
        }
    } else {
        const int N = 64 * 49 * 1024;
        for (int i = tid0; i < N; i += stride) LFo[i] = (__bf16)localf[i];
    }
}

// ---------------- init: h0 = q@Wh^T, c0 = q@Wc^T, o0 = g@Wg2o^T + b ----------------
__global__ void init_kernel(
    const float* q, const float* g,
    const float* Wh, const float* Wc, const float* Wg2o, const float* bg2o,
    __bf16* h0b, float* c0f, __bf16* o0b)
{
    int z = blockIdx.z;
    const float* A; const float* B; int K;
    if (z == 0)      { A = q; B = Wh;   K = 512; }
    else if (z == 1) { A = q; B = Wc;   K = 512; }
    else             { A = g; B = Wg2o; K = 2048; }
    int n0 = blockIdx.x * 64, m0 = blockIdx.y * 16;
    __shared__ float As[32][16];
    __shared__ float Bs[32][64];
    int tid = threadIdx.x;
    int n = tid & 63, tyq = tid >> 6;
    float acc[4] = {0.f, 0.f, 0.f, 0.f};
    for (int k0 = 0; k0 < K; k0 += 32) {
        {
            int idx = tid * 2, row = idx >> 5, kk = idx & 31;
            const float* ar = A + (m0 + row) * K + k0 + kk;
            As[kk][row] = ar[0];
            As[kk + 1][row] = ar[1];
        }
        {
            int row = tid >> 2, kk = (tid & 3) * 8;
            const float* br = B + (n0 + row) * K + k0 + kk;
            float4 v0 = *(const float4*)br;
            float4 v1 = *(const float4*)(br + 4);
            Bs[kk + 0][row] = v0.x; Bs[kk + 1][row] = v0.y;
            Bs[kk + 2][row] = v0.z; Bs[kk + 3][row] = v0.w;
            Bs[kk + 4][row] = v1.x; Bs[kk + 5][row] = v1.y;
            Bs[kk + 6][row] = v1.z; Bs[kk + 7][row] = v1.w;
        }
        __syncthreads();
        #pragma unroll
        for (int k = 0; k < 32; k++) {
            float4 a = *(const float4*)&As[k][tyq * 4];
            float b = Bs[k][n];
            acc[0] += a.x * b; acc[1] += a.y * b; acc[2] += a.z * b; acc[3] += a.w * b;
        }
        __syncthreads();
    }
    int ng = n0 + n;
    #pragma unroll
    for (int i = 0; i < 4; i++) {
        int m = m0 + tyq * 4 + i;
        float v = acc[i];
        if (z == 0)      { h0b[m * 512 + ng] = (__bf16)v; }
        else if (z == 1) { c0f[m * 512 + ng] = v; }
        else             { o0b[m * 512 + ng] = (__bf16)(v + bg2o[ng]); }
    }
}

// ---------------- attn_proj = localf @ W_attn^T -> bf16 [3136,512], MFMA ----------------
__global__ __launch_bounds__(256) void attnproj_kernel(
    const float* Af, const float* Bf, __bf16* APo)
{
    __shared__ __bf16 As[64][72];
    __shared__ __bf16 Bs[64][72];
    int tid = threadIdx.x;
    int m0 = blockIdx.x * 64, n0 = blockIdx.y * 64;
    int w = tid >> 6, lane = tid & 63, row16 = lane & 15, kg = lane >> 4;
    f32x4 acc[4] = {};
    for (int k0 = 0; k0 < 1024; k0 += 64) {
        int r = tid >> 2, col = (tid & 3) * 16;
        const float* ap = Af + (size_t)(m0 + r) * 1024 + k0 + col;
        const float* bp = Bf + (size_t)(n0 + r) * 1024 + k0 + col;
        bf16x8 va0, va1, vb0, vb1;
        #pragma unroll
        for (int u = 0; u < 8; u++) {
            va0[u] = (__bf16)ap[u]; va1[u] = (__bf16)ap[u + 8];
            vb0[u] = (__bf16)bp[u]; vb1[u] = (__bf16)bp[u + 8];
        }
        *(bf16x8*)&As[r][col] = va0; *(bf16x8*)&As[r][col + 8] = va1;
        *(bf16x8*)&Bs[r][col] = vb0; *(bf16x8*)&Bs[r][col + 8] = vb1;
        __syncthreads();
        #pragma unroll
        for (int kt = 0; kt < 2; kt++) {
            bf16x8 af = *(const bf16x8*)&As[w * 16 + row16][kt * 32 + kg * 8];
            #pragma unroll
            for (int j = 0; j < 4; j++) {
                bf16x8 bfv = *(const bf16x8*)&Bs[j * 16 + row16][kt * 32 + kg * 8];
                acc[j] = mfma_bf16(af, bfv, acc[j]);
            }
        }
        __syncthreads();
    }
    #pragma unroll
    for (int j = 0; j < 4; j++)
        #pragma unroll
        for (int r = 0; r < 4; r++)
            APo[(size_t)(m0 + w * 16 + kg * 4 + r) * 512 + n0 + j * 16 + row16] =
                (__bf16)acc[j][r];
}

// ---------------- persistent step-loop kernel (grid = 64 blocks) ----------------
// Per-step SLOT buffers (HS/AS/OS) are never reused within the kernel, so
// cross-block reads are plain cached vector loads (first touch per reader L2);
// writers use sc1 write-through stores that land in the memory-side cache.
__global__ __launch_bounds__(256) void loop_kernel(
    const __bf16* Yall, const __bf16* WG, const float* BG,
    const __bf16* WU, const float* bu,
    const __bf16* APb, const __bf16* LFb, const float* CF0,
    __bf16* OS, __bf16* HS, __bf16* AS, unsigned* FL)
{
    __shared__ float S[64][33];
    __shared__ float Cs[64][8];
    __shared__ float esh[64];
    __shared__ float ash[64];
    int tid = threadIdx.x;
    int blk = blockIdx.x;
    int w = tid >> 6, lane = tid & 63, row16 = lane & 15, kg = lane >> 4;

    // load c0 slice (units [8*blk, 8*blk+8)) into LDS — block-local forever
    {
        int b = tid >> 2, u0 = (tid & 3) * 2;
        Cs[b][u0]     = CF0[b * 512 + blk * 8 + u0];
        Cs[b][u0 + 1] = CF0[b * 512 + blk * 8 + u0 + 1];
    }
    __syncthreads();

    unsigned bgen = 0;
    for (int t = 0; t < 32; t++) {
        // ---- Phase A: gates = [y|o|h] @ WG^T (wave = 16-batch m-tile, full K),
        //      LSTM pointwise -> h (sc1 to HS[t+1]), c (LDS) ----
        {
            const __bf16* Yt = Yall + t * 16384;
            const __bf16* Op = OS + t * 32768;
            const __bf16* Hp = HS + t * 32768;
            int n0 = blk * 32;
            f32x4 acc[2] = {};
            #pragma unroll
            for (int kt = 0; kt < 40; kt++) {
                int k0 = kt * 32;
                bf16x8 af;
                if (k0 < 256)      af = ldb8(Yt + (w * 16 + row16) * 256 + k0 + kg * 8);
                else if (k0 < 768) af = ldb8(Op + (w * 16 + row16) * 512 + (k0 - 256) + kg * 8);
                else               af = ldb8(Hp + (w * 16 + row16) * 512 + (k0 - 768) + kg * 8);
                #pragma unroll
                for (int nt = 0; nt < 2; nt++) {
                    bf16x8 bfv = ldb8(WG + (size_t)(n0 + nt * 16 + row16) * 1280 + k0 + kg * 8);
                    acc[nt] = mfma_bf16(af, bfv, acc[nt]);
                }
            }
            #pragma unroll
            for (int nt = 0; nt < 2; nt++)
                #pragma unroll
                for (int r = 0; r < 4; r++)
                    S[w * 16 + kg * 4 + r][nt * 16 + row16] = acc[nt][r];
            __syncthreads();
            {
                int b = tid >> 2, u0 = (tid & 3) * 2;
                float h2[2];
                #pragma unroll
                for (int uu = 0; uu < 2; uu++) {
                    int u = u0 + uu;
                    float gi = S[b][u * 4 + 0] + BG[n0 + u * 4 + 0];
                    float gf = S[b][u * 4 + 1] + BG[n0 + u * 4 + 1];
                    float gg = S[b][u * 4 + 2] + BG[n0 + u * 4 + 2];
                    float go = S[b][u * 4 + 3] + BG[n0 + u * 4 + 3];
                    float cp = Cs[b][u];
                    float cn = sigf(gf) * cp + sigf(gi) * tanhf(gg);
                    h2[uu] = sigf(go) * tanhf(cn);
                    Cs[b][u] = cn;
                }
                union { __bf16 h[2]; unsigned v; } pk;
                pk.h[0] = (__bf16)h2[0]; pk.h[1] = (__bf16)h2[1];
                stc_u32((unsigned*)(HS + (t + 1) * 32768 + b * 512 + blk * 8 + u0), pk.v);
            }
        }
        gbar(FL, blk, ++bgen);

        // ---- Phase B: attention (block = batch) -> a (sc1 to AS[t+1]) ----
        {
            int b = blk;
            const __bf16* hb = HS + (t + 1) * 32768 + b * 512;
            bf16x8 h8 = ldb8(hb + lane * 8);
            for (int r = w; r < 49; r += 4) {
                bf16x8 ap8 = ldb8(APb + (size_t)(b * 49 + r) * 512 + lane * 8);
                float s = 0.f;
                #pragma unroll
                for (int u = 0; u < 8; u++) s += (float)ap8[u] * (float)h8[u];
                #pragma unroll
                for (int off = 32; off > 0; off >>= 1) s += __shfl_xor(s, off);
                if (lane == 0) esh[r] = s;
            }
            __syncthreads();
            if (tid < 64) {
                float v = (tid < 49) ? esh[tid] : -3.0e38f;
                float mx = v;
                #pragma unroll
                for (int off = 32; off > 0; off >>= 1) mx = fmaxf(mx, __shfl_xor(mx, off));
                float ex = (tid < 49) ? expf(v - mx) : 0.0f;
                float sm = ex;
                #pragma unroll
                for (int off = 32; off > 0; off >>= 1) sm += __shfl_xor(sm, off);
                if (tid < 49) ash[tid] = ex / sm;
            }
            __syncthreads();
            float a0 = 0.f, a1 = 0.f, a2 = 0.f, a3 = 0.f;
            const __bf16* lb = LFb + (size_t)b * 49 * 1024 + tid * 4;
            for (int r = 0; r < 49; r++) {
                float wt = ash[r];
                bf16x4 lf = *(const bf16x4*)(lb + r * 1024);
                a0 += wt * (float)lf[0]; a1 += wt * (float)lf[1];
                a2 += wt * (float)lf[2]; a3 += wt * (float)lf[3];
            }
            union { __bf16 b4[4]; unsigned u2[2]; } pk;
            pk.b4[0] = (__bf16)a0; pk.b4[1] = (__bf16)a1;
            pk.b4[2] = (__bf16)a2; pk.b4[3] = (__bf16)a3;
            unsigned* ao = (unsigned*)(AS + (size_t)(t + 1) * 65536 + b * 1024 + tid * 4);
            stc_u32(ao + 0, pk.u2[0]);
            stc_u32(ao + 1, pk.u2[1]);
        }
        gbar(FL, blk, ++bgen);

        // ---- Phase C: o = tanh([a|h] @ Wu^T + b_u), blocks 0..31 ----
        if (blk < 32) {
            int n0c = blk * 16;           // 16 units per block
            int mt = w;                   // wave = 16-batch m-tile
            const __bf16* Ab = AS + (size_t)(t + 1) * 65536;
            const __bf16* Hb = HS + (t + 1) * 32768;
            f32x4 acc = {};
            #pragma unroll
            for (int kt = 0; kt < 48; kt++) {
                int k0 = kt * 32;
                bf16x8 af;
                if (k0 < 1024) af = ldb8(Ab + (mt * 16 + row16) * 1024 + k0 + kg * 8);
                else           af = ldb8(Hb + (mt * 16 + row16) * 512 + (k0 - 1024) + kg * 8);
                bf16x8 bfv = ldb8(WU + (size_t)(n0c + row16) * 1536 + k0 + kg * 8);
                acc = mfma_bf16(af, bfv, acc);
            }
            int n = n0c + row16;
            float bun = bu[n];
            __bf16* Oo = OS + (t + 1) * 32768;
            #pragma unroll
            for (int r = 0; r < 4; r++) {
                int m = mt * 16 + kg * 4 + r;
                stc_bf16(&Oo[m * 512 + n], tanhf(acc[r] + bun));
            }
        }
        gbar(FL, blk, ++bgen);
    }
}

// ---------------- vocab: logits = O @ Wv^T + b, 128x128 LDS-tiled MFMA ----------------
// B operand converted f32 -> bf16 during LDS staging (no WV buffer needed).
__global__ __launch_bounds__(256) void vocab_kernel(
    const __bf16* A, const float* Wv, const float* bv, float* out)
{
    __shared__ __bf16 As[128][72];
    __shared__ __bf16 Bs[128][72];
    int tid = threadIdx.x;
    int m0 = blockIdx.x * 128;   // 16 mblk
    int n0 = blockIdx.y * 128;   // 79 nblk
    int w = tid >> 6, lane = tid & 63, row16 = lane & 15, kg = lane >> 4;
    int mw = (w & 1) * 64, nw = (w >> 1) * 64;
    f32x4 acc[4][4] = {};
    for (int k0 = 0; k0 < 512; k0 += 64) {
        #pragma unroll
        for (int q = 0; q < 2; q++) {
            int c = q * 256 + tid;
            int r = c >> 2, col = (c & 3) * 16;
            bf16x8 v0 = ldb8(A + (size_t)(m0 + r) * 512 + k0 + col);
            bf16x8 v1 = ldb8(A + (size_t)(m0 + r) * 512 + k0 + col + 8);
            *(bf16x8*)&As[r][col] = v0;
            *(bf16x8*)&As[r][col + 8] = v1;
            bf16x8 u0, u1;
            int nrow = n0 + r;
            if (nrow < 10000) {
                const float* bp = Wv + (size_t)nrow * 512 + k0 + col;
                #pragma unroll
                for (int u = 0; u < 8; u++) {
                    u0[u] = (__bf16)bp[u];
                    u1[u] = (__bf16)bp[u + 8];
                }
            } else {
                u0 = (bf16x8)(__bf16)0.0f;
                u1 = (bf16x8)(__bf16)0.0f;
            }
            *(bf16x8*)&Bs[r][col] = u0;
            *(bf16x8*)&Bs[r][col + 8] = u1;
        }
        __syncthreads();
        #pragma unroll
        for (int kt = 0; kt < 2; kt++) {
            bf16x8 af[4], bfr[4];
            #pragma unroll
            for (int i = 0; i < 4; i++)
                af[i] = *(const bf16x8*)&As[mw + i * 16 + row16][kt * 32 + kg * 8];
            #pragma unroll
            for (int j = 0; j < 4; j++)
                bfr[j] = *(const bf16x8*)&Bs[nw + j * 16 + row16][kt * 32 + kg * 8];
            #pragma unroll
            for (int i = 0; i < 4; i++)
                #pragma unroll
                for (int j = 0; j < 4; j++)
                    acc[i][j] = mfma_bf16(af[i], bfr[j], acc[i][j]);
        }
        __syncthreads();
    }
    #pragma unroll
    for (int j = 0; j < 4; j++) {
        int n = n0 + nw + j * 16 + row16;
        if (n < 10000) {
            float bvn = bv[n];
            #pragma unroll
            for (int i = 0; i < 4; i++) {
                #pragma unroll
                for (int r = 0; r < 4; r++) {
                    int m = m0 + mw + i * 16 + kg * 4 + r;   // m = t*64 + b
                    int tt = m >> 6, b = m & 63;
                    out[(size_t)(b * 32 + tt) * 10000 + n] = acc[i][j][r] + bvn;
                }
            }
        }
    }
}

extern "C" void kernel_launch(void* const* d_in, const int* in_sizes, int n_in,
                              void* d_out, int out_size, void* d_ws, size_t ws_size,
                              hipStream_t stream) {
    (void)in_sizes; (void)n_in; (void)out_size; (void)ws_size;
    const float* localf  = (const float*)d_in[0];
    const float* globalf = (const float*)d_in[1];
    const float* qvec    = (const float*)d_in[2];
    const int*   answers = (const int*)d_in[3];
    const float* emb     = (const float*)d_in[4];
    const float* Wg2o    = (const float*)d_in[5];
    const float* bg2o    = (const float*)d_in[6];
    const float* Wh      = (const float*)d_in[7];
    const float* Wc      = (const float*)d_in[8];
    const float* Wih     = (const float*)d_in[9];
    const float* Whh     = (const float*)d_in[10];
    const float* bih     = (const float*)d_in[11];
    const float* bhh     = (const float*)d_in[12];
    const float* Wattn   = (const float*)d_in[13];
    const float* Wu      = (const float*)d_in[14];
    const float* bu      = (const float*)d_in[15];
    const float* Wvocab  = (const float*)d_in[16];
    const float* bvocab  = (const float*)d_in[17];
    float* out = (float*)d_out;

    char* ws = (char*)d_ws;
    __bf16* WG  = (__bf16*)(ws + 0);          // 2048*1280 bf16 (gate-perm [W_ih|W_hh])   5,242,880
    __bf16* WU  = (__bf16*)(ws + 5242880);    // 512*1536 bf16                            1,572,864
    __bf16* Y   = (__bf16*)(ws + 6815744);    // 32*64*256 bf16                           1,048,576
    float*  BG  = (float*) (ws + 7864320);    // 2048 f32 (b_ih+b_hh perm)                    8,192
    __bf16* OS  = (__bf16*)(ws + 7872512);    // 33 slots * 64*512 bf16 (o; slot0=o0)     2,162,688
    __bf16* HS  = (__bf16*)(ws + 10035200);   // 33 slots * 64*512 bf16 (h; slot0=h0)     2,162,688
    __bf16* AS  = (__bf16*)(ws + 12197888);   // 33 slots * 64*1024 bf16 (a)              4,325,376
    float*  CF0 = (float*) (ws + 16523264);   // 64*512 f32 (c0)                            131,072
    __bf16* APb = (__bf16*)(ws + 16654336);   // 64*49*512 bf16 (attn_proj)               3,211,264
    __bf16* LFb = (__bf16*)(ws + 19865600);   // 64*49*1024 bf16 (local features)         6,422,528
    unsigned* FL = (unsigned*)(ws + 26288128); // 64 u32 flags                                 256
    // total: 26,288,384 B  (within r1-verified >=27.5MB workspace)

    hipMemsetAsync(FL, 0, 256, stream);
    convert_kernel<<<dim3(1024, 1, 4), 256, 0, stream>>>(
        Wih, Whh, bih, bhh, Wu, emb, answers, localf,
        WG, BG, WU, Y, LFb);
    init_kernel<<<dim3(8, 4, 3), 256, 0, stream>>>(
        qvec, globalf, Wh, Wc, Wg2o, bg2o, HS, CF0, OS);
    attnproj_kernel<<<dim3(49, 8), 256, 0, stream>>>(localf, Wattn, APb);
    loop_kernel<<<GRID_BLKS, 256, 0, stream>>>(
        Y, WG, BG, WU, bu, APb, LFb, CF0, OS, HS, AS, FL);
    vocab_kernel<<<dim3(16, 79), 256, 0, stream>>>(OS + 32768, Wvocab, bvocab, out);
}